// Round 1
// baseline (453.528 us; speedup 1.0000x reference)
//
#include <hip/hip_runtime.h>

// Problem constants
// B=8, S=512, DM=1024, H=16, D=64
#define Bsz 8
#define Ssz 512
#define DMsz 1024
#define Hsz 16
#define Dsz 64

using short8 = __attribute__((ext_vector_type(8))) short;
using f32x4  = __attribute__((ext_vector_type(4))) float;

__device__ __forceinline__ unsigned short f2bf(float x) {
    union { float f; unsigned u; } v; v.f = x;
    unsigned u = v.u;
    unsigned r = (u + 0x7fffu + ((u >> 16) & 1u)) >> 16;   // RNE
    return (unsigned short)r;
}
__device__ __forceinline__ float bf2f(unsigned short h) {
    union { unsigned u; float f; } v; v.u = ((unsigned)h) << 16;
    return v.f;
}

// ---------------------------------------------------------------------------
// Kernel 1: feature precompute
// G[b,h,q,k] = cw1 * relu( sum_c fcw[h,c]*f_c + fcb[h] )   (bf16)
// f = (dist_emb[dist], speaker, disc_emb[disc]*(disc!=0), cooc_emb[cooc]*(cooc!=0))
// ---------------------------------------------------------------------------
__global__ __launch_bounds__(256) void feat_kernel(
    const int* __restrict__ dist_adj, const float* __restrict__ spk,
    const int* __restrict__ disc_adj, const int* __restrict__ cooc_adj,
    const float* __restrict__ dist_emb, const float* __restrict__ disc_emb,
    const float* __restrict__ cooc_emb, const float* __restrict__ fcw,
    const float* __restrict__ fcb, const float* __restrict__ cw,
    unsigned short* __restrict__ G)
{
    __shared__ float s_dist[1023];
    __shared__ float s_disc[17];
    __shared__ float s_cooc[6];
    __shared__ float s_fcw[64];
    __shared__ float s_fcb[16];
    int tid = threadIdx.x;
    for (int i = tid; i < 1023; i += 256) s_dist[i] = dist_emb[i];
    if (tid < 17) s_disc[tid] = disc_emb[tid];
    if (tid < 6)  s_cooc[tid] = cooc_emb[tid];
    if (tid < 64) s_fcw[tid]  = fcw[tid];
    if (tid < 16) s_fcb[tid]  = fcb[tid];
    __syncthreads();
    float cw1 = cw[1];

    size_t e = ((size_t)blockIdx.x * 256 + tid) * 4;   // 4 consecutive k per thread
    int b   = (int)(e >> 18);              // S*S = 262144 = 2^18
    int rem = (int)(e & 262143);
    int q = rem >> 9, k0 = rem & 511;

    int4   dd = *(const int4*)(dist_adj + e);
    float4 ss = *(const float4*)(spk + e);
    int4   dc = *(const int4*)(disc_adj + e);
    int4   cc = *(const int4*)(cooc_adj + e);

    float f0[4], f1[4], f2[4], f3[4];
    f0[0] = s_dist[dd.x]; f0[1] = s_dist[dd.y]; f0[2] = s_dist[dd.z]; f0[3] = s_dist[dd.w];
    f1[0] = ss.x; f1[1] = ss.y; f1[2] = ss.z; f1[3] = ss.w;
    f2[0] = dc.x ? s_disc[dc.x] : 0.f; f2[1] = dc.y ? s_disc[dc.y] : 0.f;
    f2[2] = dc.z ? s_disc[dc.z] : 0.f; f2[3] = dc.w ? s_disc[dc.w] : 0.f;
    f3[0] = cc.x ? s_cooc[cc.x] : 0.f; f3[1] = cc.y ? s_cooc[cc.y] : 0.f;
    f3[2] = cc.z ? s_cooc[cc.z] : 0.f; f3[3] = cc.w ? s_cooc[cc.w] : 0.f;

    size_t gb = (((size_t)b * 16) * 512 + q) * 512 + k0;   // h=0 offset
#pragma unroll
    for (int h = 0; h < 16; ++h) {
        float w0 = s_fcw[h*4+0], w1 = s_fcw[h*4+1], w2 = s_fcw[h*4+2], w3 = s_fcw[h*4+3];
        float bb = s_fcb[h];
        ushort4 o;
        float v0 = fmaxf(w0*f0[0] + w1*f1[0] + w2*f2[0] + w3*f3[0] + bb, 0.f) * cw1;
        float v1 = fmaxf(w0*f0[1] + w1*f1[1] + w2*f2[1] + w3*f3[1] + bb, 0.f) * cw1;
        float v2 = fmaxf(w0*f0[2] + w1*f1[2] + w2*f2[2] + w3*f3[2] + bb, 0.f) * cw1;
        float v3 = fmaxf(w0*f0[3] + w1*f1[3] + w2*f2[3] + w3*f3[3] + bb, 0.f) * cw1;
        o.x = f2bf(v0); o.y = f2bf(v1); o.z = f2bf(v2); o.w = f2bf(v3);
        *(ushort4*)(G + gb + (size_t)h * 262144) = o;
    }
}

// ---------------------------------------------------------------------------
// GEMM body: C[m,n] = sum_k A[m,k]*W[n,k] + bias[n]
// M=4096, N=1024, K=1024. 128x128 block tile, 4 waves (2x2), 16x16x32 bf16 MFMA.
// ABF16: A is bf16 (else fp32, converted during staging).
// OMODE 0: write bf16 split-head layout [b,h,s,d]; OMODE 1: write fp32 [m][n].
// ---------------------------------------------------------------------------
template<int ABF16, int OMODE>
__device__ __forceinline__ void gemm_body(const void* __restrict__ Ap,
                                          const float* __restrict__ W,
                                          const float* __restrict__ bias,
                                          void* __restrict__ outp)
{
    __shared__ __align__(16) unsigned short As[128][40];
    __shared__ __align__(16) unsigned short Bs[128][40];
    int tid = threadIdx.x;
    int lane = tid & 63, wid = tid >> 6;
    int wx = wid & 1, wy = wid >> 1;
    int lanelo = lane & 15, hi8 = (lane >> 4) * 8;
    int m0 = blockIdx.y * 128, n0 = blockIdx.x * 128;

    f32x4 acc[4][4];
#pragma unroll
    for (int i = 0; i < 4; ++i)
#pragma unroll
        for (int j = 0; j < 4; ++j) {
            acc[i][j][0] = 0.f; acc[i][j][1] = 0.f; acc[i][j][2] = 0.f; acc[i][j][3] = 0.f;
        }

    for (int kk = 0; kk < 32; ++kk) {
        int k0 = kk * 32;
        __syncthreads();
        if (ABF16) {
            const unsigned short* A = (const unsigned short*)Ap;
#pragma unroll
            for (int p = 0; p < 2; ++p) {
                int c = p * 256 + tid;
                int row = c >> 2, kc = (c & 3) * 8;
                uint4 v = *(const uint4*)(A + (size_t)(m0 + row) * 1024 + k0 + kc);
                *(uint4*)&As[row][kc] = v;
            }
        } else {
            const float* A = (const float*)Ap;
#pragma unroll
            for (int p = 0; p < 4; ++p) {
                int c = p * 256 + tid;
                int row = c >> 3, kc = (c & 7) * 4;
                float4 v = *(const float4*)(A + (size_t)(m0 + row) * 1024 + k0 + kc);
                ushort4 hv; hv.x = f2bf(v.x); hv.y = f2bf(v.y); hv.z = f2bf(v.z); hv.w = f2bf(v.w);
                *(ushort4*)&As[row][kc] = hv;
            }
        }
#pragma unroll
        for (int p = 0; p < 4; ++p) {
            int c = p * 256 + tid;
            int row = c >> 3, kc = (c & 7) * 4;
            float4 v = *(const float4*)(W + (size_t)(n0 + row) * 1024 + k0 + kc);
            ushort4 hv; hv.x = f2bf(v.x); hv.y = f2bf(v.y); hv.z = f2bf(v.z); hv.w = f2bf(v.w);
            *(ushort4*)&Bs[row][kc] = hv;
        }
        __syncthreads();

        short8 af[4], bfr[4];
#pragma unroll
        for (int i = 0; i < 4; ++i)
            af[i] = *(const short8*)&As[wy*64 + i*16 + lanelo][hi8];
#pragma unroll
        for (int j = 0; j < 4; ++j)
            bfr[j] = *(const short8*)&Bs[wx*64 + j*16 + lanelo][hi8];
#pragma unroll
        for (int i = 0; i < 4; ++i)
#pragma unroll
            for (int j = 0; j < 4; ++j)
                acc[i][j] = __builtin_amdgcn_mfma_f32_16x16x32_bf16(af[i], bfr[j], acc[i][j], 0, 0, 0);
    }

    // Epilogue. C/D layout: col = lane&15, row = (lane>>4)*4 + reg  [m89/m91]
    float bia[4];
#pragma unroll
    for (int j = 0; j < 4; ++j) bia[j] = bias[n0 + wx*64 + j*16 + lanelo];
#pragma unroll
    for (int i = 0; i < 4; ++i) {
        int mbase = m0 + wy*64 + i*16 + (lane >> 4) * 4;
#pragma unroll
        for (int j = 0; j < 4; ++j) {
            int n = n0 + wx*64 + j*16 + lanelo;
#pragma unroll
            for (int r = 0; r < 4; ++r) {
                int m = mbase + r;
                float val = acc[i][j][r] + bia[j];
                if (OMODE == 0) {
                    unsigned short* o = (unsigned short*)outp;
                    o[((size_t)((m >> 9) * 16 + (n >> 6)) * 512 + (m & 511)) * 64 + (n & 63)] = f2bf(val);
                } else {
                    float* o = (float*)outp;
                    o[(size_t)m * 1024 + n] = val;
                }
            }
        }
    }
}

__global__ __launch_bounds__(256) void gemm_qkv(
    const float* __restrict__ q, const float* __restrict__ k, const float* __restrict__ v,
    const float* __restrict__ Wq, const float* __restrict__ Wk, const float* __restrict__ Wv,
    const float* __restrict__ bq, const float* __restrict__ bk, const float* __restrict__ bv,
    unsigned short* Qb, unsigned short* Kb, unsigned short* Vb)
{
    int z = blockIdx.z;
    const float* A    = (z == 0) ? q  : ((z == 1) ? k  : v);
    const float* W    = (z == 0) ? Wq : ((z == 1) ? Wk : Wv);
    const float* bias = (z == 0) ? bq : ((z == 1) ? bk : bv);
    unsigned short* o = (z == 0) ? Qb : ((z == 1) ? Kb : Vb);
    gemm_body<0, 0>(A, W, bias, o);
}

__global__ __launch_bounds__(256) void gemm_proj(
    const unsigned short* __restrict__ xh, const float* __restrict__ Wo,
    const float* __restrict__ bo, float* __restrict__ out)
{
    gemm_body<1, 1>(xh, Wo, bo, out);
}

// ---------------------------------------------------------------------------
// Transpose V: [b,h,s,d] bf16 -> Vt [b,h,d,s] bf16
// ---------------------------------------------------------------------------
__global__ __launch_bounds__(256) void transpose_v(const unsigned short* __restrict__ Vb,
                                                   unsigned short* __restrict__ Vt)
{
    __shared__ __align__(16) unsigned short T[64][72];
    int tid = threadIdx.x;
    int s0 = blockIdx.x * 64;
    int bh = blockIdx.z * 16 + blockIdx.y;
#pragma unroll
    for (int p = 0; p < 2; ++p) {
        int c = p * 256 + tid;
        int row = c >> 3, kc = (c & 7) * 8;
        uint4 v = *(const uint4*)(Vb + ((size_t)bh * 512 + s0 + row) * 64 + kc);
        *(uint4*)&T[row][kc] = v;
    }
    __syncthreads();
#pragma unroll
    for (int p = 0; p < 2; ++p) {
        int c = p * 256 + tid;
        int d = c >> 3, sc = (c & 7) * 8;
        unsigned vv[4];
#pragma unroll
        for (int i = 0; i < 4; ++i) {
            unsigned lo = T[sc + 2*i][d];
            unsigned hi = T[sc + 2*i + 1][d];
            vv[i] = lo | (hi << 16);
        }
        uint4 o; o.x = vv[0]; o.y = vv[1]; o.z = vv[2]; o.w = vv[3];
        *(uint4*)(Vt + ((size_t)bh * 64 + d) * 512 + s0 + sc) = o;
    }
}

// ---------------------------------------------------------------------------
// Attention: per block (qt, h, b): 64 q-rows, full 512 k, 4 waves x 16 rows.
// E = relu(cw0*(QK/8) + G + cb); P = mask ? exp(E) : 0 (no max-sub; |E| tiny)
// attn = P / rowsum (written fp32); x = (P V) / rowsum (written bf16 to xh)
// ---------------------------------------------------------------------------
__global__ __launch_bounds__(256, 2) void attn_kernel(
    const unsigned short* __restrict__ Qb, const unsigned short* __restrict__ Kb,
    const unsigned short* __restrict__ Vt, const unsigned short* __restrict__ G,
    const int* __restrict__ mask, const float* __restrict__ cw,
    const float* __restrict__ cb, float* __restrict__ attn_out,
    unsigned short* __restrict__ xh)
{
    __shared__ __align__(16) unsigned short Qs[64][72];
    __shared__ __align__(16) unsigned short Ks[128][72];
    __shared__ __align__(16) unsigned short Vs[64][40];
    __shared__ __align__(16) unsigned short Ps[4][16][40];
    __shared__ int s_mask[512];

    int tid = threadIdx.x;
    int lane = tid & 63, w = tid >> 6;
    int lanelo = lane & 15, hi8 = (lane >> 4) * 8;
    int qt = blockIdx.x, h = blockIdx.y, b = blockIdx.z;
    int bh = b * 16 + h;
    float qs  = cw[0] * 0.125f;   // cw0 / sqrt(64)
    float cbv = cb[0];

    s_mask[tid]       = mask[b * 512 + tid];
    s_mask[tid + 256] = mask[b * 512 + tid + 256];
#pragma unroll
    for (int p = 0; p < 2; ++p) {
        int c = p * 256 + tid;
        int row = c >> 3, kc = (c & 7) * 8;
        uint4 v = *(const uint4*)(Qb + ((size_t)bh * 512 + qt * 64 + row) * 64 + kc);
        *(uint4*)&Qs[row][kc] = v;
    }
    __syncthreads();

    short8 aq[2];
    aq[0] = *(const short8*)&Qs[w * 16 + lanelo][hi8];
    aq[1] = *(const short8*)&Qs[w * 16 + lanelo][32 + hi8];
    int qrow = qt * 64 + w * 16 + (lane >> 4) * 4;   // base of this lane's 4 q rows

    float P[32][4];
#pragma unroll
    for (int kt = 0; kt < 4; ++kt) {
        __syncthreads();
#pragma unroll
        for (int p = 0; p < 4; ++p) {
            int c = p * 256 + tid;
            int row = c >> 3, kc = (c & 7) * 8;
            uint4 v = *(const uint4*)(Kb + ((size_t)bh * 512 + kt * 128 + row) * 64 + kc);
            *(uint4*)&Ks[row][kc] = v;
        }
        __syncthreads();
#pragma unroll
        for (int j = 0; j < 8; ++j) {
            short8 b0 = *(const short8*)&Ks[j * 16 + lanelo][hi8];
            short8 b1 = *(const short8*)&Ks[j * 16 + lanelo][32 + hi8];
            f32x4 acc; acc[0] = 0.f; acc[1] = 0.f; acc[2] = 0.f; acc[3] = 0.f;
            acc = __builtin_amdgcn_mfma_f32_16x16x32_bf16(aq[0], b0, acc, 0, 0, 0);
            acc = __builtin_amdgcn_mfma_f32_16x16x32_bf16(aq[1], b1, acc, 0, 0, 0);
            int jj = kt * 8 + j;
            int kcol = jj * 16 + lanelo;
            int mk = s_mask[kcol];
            const unsigned short* gp = G + ((size_t)bh * 512 + qrow) * 512 + kcol;
#pragma unroll
            for (int r = 0; r < 4; ++r) {
                float e = qs * acc[r] + bf2f(gp[(size_t)r * 512]) + cbv;
                e = fmaxf(e, 0.f);
                P[jj][r] = mk ? __expf(e) : 0.f;
            }
        }
    }

    // row sums -> inverse (lanes 0..15 of each quad-group hold disjoint cols)
    float inv[4];
#pragma unroll
    for (int r = 0; r < 4; ++r) {
        float s = 0.f;
#pragma unroll
        for (int jj = 0; jj < 32; ++jj) s += P[jj][r];
        s += __shfl_xor(s, 1, 64);
        s += __shfl_xor(s, 2, 64);
        s += __shfl_xor(s, 4, 64);
        s += __shfl_xor(s, 8, 64);
        inv[r] = 1.0f / s;
    }

    // normalized attention write (fp32)
    {
        float* ap = attn_out + ((size_t)bh * 512 + qrow) * 512 + lanelo;
#pragma unroll
        for (int jj = 0; jj < 32; ++jj)
#pragma unroll
            for (int r = 0; r < 4; ++r)
                ap[(size_t)r * 512 + jj * 16] = P[jj][r] * inv[r];
    }

    // PV: x = (P V) * inv.  P C-layout -> A-operand via per-wave LDS round-trip.
    f32x4 xacc[4];
#pragma unroll
    for (int jf = 0; jf < 4; ++jf) { xacc[jf][0]=0.f; xacc[jf][1]=0.f; xacc[jf][2]=0.f; xacc[jf][3]=0.f; }
#pragma unroll
    for (int ks = 0; ks < 16; ++ks) {
        __syncthreads();
        {
            int d = tid >> 2, kc = (tid & 3) * 8;
            uint4 v = *(const uint4*)(Vt + ((size_t)bh * 64 + d) * 512 + ks * 32 + kc);
            *(uint4*)&Vs[d][kc] = v;
        }
#pragma unroll
        for (int ff = 0; ff < 2; ++ff) {
            int f = ks * 2 + ff;
#pragma unroll
            for (int r = 0; r < 4; ++r)
                Ps[w][(lane >> 4) * 4 + r][ff * 16 + lanelo] = f2bf(P[f][r]);
        }
        __syncthreads();
        short8 ap8 = *(const short8*)&Ps[w][lanelo][hi8];
#pragma unroll
        for (int jf = 0; jf < 4; ++jf) {
            short8 bv = *(const short8*)&Vs[jf * 16 + lanelo][hi8];
            xacc[jf] = __builtin_amdgcn_mfma_f32_16x16x32_bf16(ap8, bv, xacc[jf], 0, 0, 0);
        }
    }

    // store x heads (bf16, merged [b*512+q][h*64+d])
#pragma unroll
    for (int jf = 0; jf < 4; ++jf) {
        int d = jf * 16 + lanelo;
#pragma unroll
        for (int r = 0; r < 4; ++r) {
            float val = xacc[jf][r] * inv[r];
            xh[((size_t)b * 512 + qrow + r) * 1024 + h * 64 + d] = f2bf(val);
        }
    }
}

// ---------------------------------------------------------------------------
extern "C" void kernel_launch(void* const* d_in, const int* in_sizes, int n_in,
                              void* d_out, int out_size, void* d_ws, size_t ws_size,
                              hipStream_t stream) {
    (void)in_sizes; (void)n_in; (void)out_size; (void)ws_size;
    const float* query    = (const float*)d_in[0];
    const float* key      = (const float*)d_in[1];
    const float* value    = (const float*)d_in[2];
    const int*   dist_adj = (const int*)d_in[3];
    const float* spk      = (const float*)d_in[4];
    const int*   disc_adj = (const int*)d_in[5];
    const int*   cooc_adj = (const int*)d_in[6];
    const int*   maskp    = (const int*)d_in[7];
    const float* Wq = (const float*)d_in[8];  const float* bq = (const float*)d_in[9];
    const float* Wk = (const float*)d_in[10]; const float* bk = (const float*)d_in[11];
    const float* Wv = (const float*)d_in[12]; const float* bv = (const float*)d_in[13];
    const float* Wo = (const float*)d_in[14]; const float* bo = (const float*)d_in[15];
    const float* dist_emb = (const float*)d_in[16];
    const float* disc_emb = (const float*)d_in[17];
    const float* cooc_emb = (const float*)d_in[18];
    const float* fcw = (const float*)d_in[19];
    const float* fcb = (const float*)d_in[20];
    const float* cw  = (const float*)d_in[21];
    const float* cbp = (const float*)d_in[22];

    char* w = (char*)d_ws;
    unsigned short* Qb = (unsigned short*)(w);                   //  8 MB
    unsigned short* Kb = (unsigned short*)(w + 8388608);         //  8 MB
    unsigned short* Vb = (unsigned short*)(w + 16777216);        //  8 MB
    unsigned short* Vt = (unsigned short*)(w + 25165824);        //  8 MB
    unsigned short* xh = (unsigned short*)(w + 33554432);        //  8 MB
    unsigned short* G  = (unsigned short*)(w + 41943040);        // 64 MB

    float* out_x    = (float*)d_out;
    float* attn_out = ((float*)d_out) + 4194304;   // B*S*DM

    feat_kernel<<<2048, 256, 0, stream>>>(dist_adj, spk, disc_adj, cooc_adj,
                                          dist_emb, disc_emb, cooc_emb, fcw, fcb, cw, G);
    gemm_qkv<<<dim3(8, 32, 3), 256, 0, stream>>>(query, key, value, Wq, Wk, Wv,
                                                 bq, bk, bv, Qb, Kb, Vb);
    transpose_v<<<dim3(8, 16, 8), 256, 0, stream>>>(Vb, Vt);
    attn_kernel<<<dim3(8, 16, 8), 256, 0, stream>>>(Qb, Kb, Vt, G, maskp, cw, cbp,
                                                    attn_out, xh);
    gemm_proj<<<dim3(8, 32), 256, 0, stream>>>(xh, Wo, bo, out_x);
}

// Round 2
// 385.806 us; speedup vs baseline: 1.1755x; 1.1755x over previous
//
#include <hip/hip_runtime.h>

// B=8, S=512, DM=1024, H=16, D=64
using short8 = __attribute__((ext_vector_type(8))) short;
using f32x4  = __attribute__((ext_vector_type(4))) float;

__device__ __forceinline__ unsigned short f2bf(float x) {
    union { float f; unsigned u; } v; v.f = x;
    unsigned u = v.u;
    unsigned r = (u + 0x7fffu + ((u >> 16) & 1u)) >> 16;   // RNE
    return (unsigned short)r;
}
__device__ __forceinline__ float bf2f(unsigned short h) {
    union { unsigned u; float f; } v; v.u = ((unsigned)h) << 16;
    return v.f;
}

__device__ __forceinline__ void async16(const void* g, void* l) {
    __builtin_amdgcn_global_load_lds(
        (const __attribute__((address_space(1))) void*)g,
        (__attribute__((address_space(3))) void*)l, 16, 0, 0);
}

// ---------------------------------------------------------------------------
// fp32 -> bf16 converters (8 elems/thread)
// ---------------------------------------------------------------------------
__global__ __launch_bounds__(256) void cvt_qkv(
    const float* __restrict__ q, const float* __restrict__ k, const float* __restrict__ v,
    unsigned short* __restrict__ dst)   // 3 x 4M elems contiguous
{
    int z = blockIdx.z;
    const float* src = (z == 0) ? q : ((z == 1) ? k : v);
    unsigned short* o = dst + (size_t)z * 4194304;
    size_t i = ((size_t)blockIdx.x * 256 + threadIdx.x) * 8;
    float4 a = *(const float4*)(src + i);
    float4 b = *(const float4*)(src + i + 4);
    ushort4 lo, hi;
    lo.x = f2bf(a.x); lo.y = f2bf(a.y); lo.z = f2bf(a.z); lo.w = f2bf(a.w);
    hi.x = f2bf(b.x); hi.y = f2bf(b.y); hi.z = f2bf(b.z); hi.w = f2bf(b.w);
    *(ushort4*)(o + i) = lo;
    *(ushort4*)(o + i + 4) = hi;
}

__global__ __launch_bounds__(256) void cvt_w(
    const float* __restrict__ wq, const float* __restrict__ wk,
    const float* __restrict__ wv, const float* __restrict__ wo,
    unsigned short* __restrict__ dst)   // 4 x 1M elems contiguous
{
    int z = blockIdx.z;
    const float* src = (z == 0) ? wq : ((z == 1) ? wk : ((z == 2) ? wv : wo));
    unsigned short* o = dst + (size_t)z * 1048576;
    size_t i = ((size_t)blockIdx.x * 256 + threadIdx.x) * 8;
    float4 a = *(const float4*)(src + i);
    float4 b = *(const float4*)(src + i + 4);
    ushort4 lo, hi;
    lo.x = f2bf(a.x); lo.y = f2bf(a.y); lo.z = f2bf(a.z); lo.w = f2bf(a.w);
    hi.x = f2bf(b.x); hi.y = f2bf(b.y); hi.z = f2bf(b.z); hi.w = f2bf(b.w);
    *(ushort4*)(o + i) = lo;
    *(ushort4*)(o + i + 4) = hi;
}

// ---------------------------------------------------------------------------
// feature precompute: G[b,h,q,k] = cw1 * relu(fcw.f + fcb)   (bf16)
// ---------------------------------------------------------------------------
__global__ __launch_bounds__(256) void feat_kernel(
    const int* __restrict__ dist_adj, const float* __restrict__ spk,
    const int* __restrict__ disc_adj, const int* __restrict__ cooc_adj,
    const float* __restrict__ dist_emb, const float* __restrict__ disc_emb,
    const float* __restrict__ cooc_emb, const float* __restrict__ fcw,
    const float* __restrict__ fcb, const float* __restrict__ cw,
    unsigned short* __restrict__ G)
{
    __shared__ float s_dist[1023];
    __shared__ float s_disc[17];
    __shared__ float s_cooc[6];
    __shared__ float s_fcw[64];
    __shared__ float s_fcb[16];
    int tid = threadIdx.x;
    for (int i = tid; i < 1023; i += 256) s_dist[i] = dist_emb[i];
    if (tid < 17) s_disc[tid] = disc_emb[tid];
    if (tid < 6)  s_cooc[tid] = cooc_emb[tid];
    if (tid < 64) s_fcw[tid]  = fcw[tid];
    if (tid < 16) s_fcb[tid]  = fcb[tid];
    __syncthreads();
    float cw1 = cw[1];

    size_t e = ((size_t)blockIdx.x * 256 + tid) * 4;
    int b   = (int)(e >> 18);
    int rem = (int)(e & 262143);
    int q = rem >> 9, k0 = rem & 511;

    int4   dd = *(const int4*)(dist_adj + e);
    float4 ss = *(const float4*)(spk + e);
    int4   dc = *(const int4*)(disc_adj + e);
    int4   cc = *(const int4*)(cooc_adj + e);

    float f0[4], f1[4], f2[4], f3[4];
    f0[0] = s_dist[dd.x]; f0[1] = s_dist[dd.y]; f0[2] = s_dist[dd.z]; f0[3] = s_dist[dd.w];
    f1[0] = ss.x; f1[1] = ss.y; f1[2] = ss.z; f1[3] = ss.w;
    f2[0] = dc.x ? s_disc[dc.x] : 0.f; f2[1] = dc.y ? s_disc[dc.y] : 0.f;
    f2[2] = dc.z ? s_disc[dc.z] : 0.f; f2[3] = dc.w ? s_disc[dc.w] : 0.f;
    f3[0] = cc.x ? s_cooc[cc.x] : 0.f; f3[1] = cc.y ? s_cooc[cc.y] : 0.f;
    f3[2] = cc.z ? s_cooc[cc.z] : 0.f; f3[3] = cc.w ? s_cooc[cc.w] : 0.f;

    size_t gb = (((size_t)b * 16) * 512 + q) * 512 + k0;
#pragma unroll
    for (int h = 0; h < 16; ++h) {
        float w0 = s_fcw[h*4+0], w1 = s_fcw[h*4+1], w2 = s_fcw[h*4+2], w3 = s_fcw[h*4+3];
        float bb = s_fcb[h];
        ushort4 o;
        o.x = f2bf(fmaxf(w0*f0[0] + w1*f1[0] + w2*f2[0] + w3*f3[0] + bb, 0.f) * cw1);
        o.y = f2bf(fmaxf(w0*f0[1] + w1*f1[1] + w2*f2[1] + w3*f3[1] + bb, 0.f) * cw1);
        o.z = f2bf(fmaxf(w0*f0[2] + w1*f1[2] + w2*f2[2] + w3*f3[2] + bb, 0.f) * cw1);
        o.w = f2bf(fmaxf(w0*f0[3] + w1*f1[3] + w2*f2[3] + w3*f3[3] + bb, 0.f) * cw1);
        *(ushort4*)(G + gb + (size_t)h * 262144) = o;
    }
}

// ---------------------------------------------------------------------------
// bf16 GEMM, m97 structure: C[m,n] = sum_k A[m,k]*W[n,k] + bias[n]
// 128x128 tile, BK=32, 4 waves (2x2), async global->LDS 16B staging.
// OMODE 0: bf16 split-head [b,h,s,d]; OMODE 1: fp32 [m][1024].
// ---------------------------------------------------------------------------
template<int OMODE>
__device__ __forceinline__ void gemm_bf16_body(
    const unsigned short* __restrict__ A, const unsigned short* __restrict__ W,
    const float* __restrict__ bias, void* __restrict__ outp, int m0, int n0)
{
    __shared__ __align__(16) unsigned short As[128 * 32];   // row-major, NO pad
    __shared__ __align__(16) unsigned short Bs[128 * 32];
    int tid = threadIdx.x;
    int lane = tid & 63, wid = tid >> 6;
    int wx = wid & 1, wy = wid >> 1;
    int lanelo = lane & 15, hi8 = (lane >> 4) * 8;
    int rowc = lane >> 2;          // row within 16-row chunk
    int colc = (lane & 3) * 8;     // k-offset (elems) within row

    f32x4 acc[4][4];
#pragma unroll
    for (int i = 0; i < 4; ++i)
#pragma unroll
        for (int j = 0; j < 4; ++j) {
            acc[i][j][0] = 0.f; acc[i][j][1] = 0.f; acc[i][j][2] = 0.f; acc[i][j][3] = 0.f;
        }

    for (int kk = 0; kk < 32; ++kk) {
        int k0 = kk * 32;
        __syncthreads();
#pragma unroll
        for (int p = 0; p < 2; ++p) {
            int c = 2 * wid + p;           // chunk 0..7
            int row = c * 16 + rowc;
            async16(A + (size_t)(m0 + row) * 1024 + k0 + colc, As + c * 512);
        }
#pragma unroll
        for (int p = 0; p < 2; ++p) {
            int c = 2 * wid + p;
            int row = c * 16 + rowc;
            async16(W + (size_t)(n0 + row) * 1024 + k0 + colc, Bs + c * 512);
        }
        __syncthreads();

        short8 af[4], bfr[4];
#pragma unroll
        for (int i = 0; i < 4; ++i)
            af[i] = *(const short8*)(As + (wy*64 + i*16 + lanelo) * 32 + hi8);
#pragma unroll
        for (int j = 0; j < 4; ++j)
            bfr[j] = *(const short8*)(Bs + (wx*64 + j*16 + lanelo) * 32 + hi8);
#pragma unroll
        for (int i = 0; i < 4; ++i)
#pragma unroll
            for (int j = 0; j < 4; ++j)
                acc[i][j] = __builtin_amdgcn_mfma_f32_16x16x32_bf16(af[i], bfr[j], acc[i][j], 0, 0, 0);
    }

    float bia[4];
#pragma unroll
    for (int j = 0; j < 4; ++j) bia[j] = bias[n0 + wx*64 + j*16 + lanelo];
#pragma unroll
    for (int i = 0; i < 4; ++i) {
        int mbase = m0 + wy*64 + i*16 + (lane >> 4) * 4;
#pragma unroll
        for (int j = 0; j < 4; ++j) {
            int n = n0 + wx*64 + j*16 + lanelo;
#pragma unroll
            for (int r = 0; r < 4; ++r) {
                int m = mbase + r;
                float val = acc[i][j][r] + bia[j];
                if (OMODE == 0) {
                    unsigned short* o = (unsigned short*)outp;
                    o[((size_t)((m >> 9) * 16 + (n >> 6)) * 512 + (m & 511)) * 64 + (n & 63)] = f2bf(val);
                } else {
                    float* o = (float*)outp;
                    o[(size_t)m * 1024 + n] = val;
                }
            }
        }
    }
}

// grid (32, 8, 3): x = m-tile (XCD-local A reuse), y = n-tile, z = tensor
__global__ __launch_bounds__(256) void gemm_qkv(
    const unsigned short* __restrict__ Abf, const unsigned short* __restrict__ Wbf,
    const float* __restrict__ bq, const float* __restrict__ bk, const float* __restrict__ bv,
    unsigned short* Qb, unsigned short* Kb, unsigned short* Vb)
{
    int z = blockIdx.z;
    const unsigned short* A = Abf + (size_t)z * 4194304;
    const unsigned short* W = Wbf + (size_t)z * 1048576;
    const float* bias = (z == 0) ? bq : ((z == 1) ? bk : bv);
    unsigned short* o = (z == 0) ? Qb : ((z == 1) ? Kb : Vb);
    gemm_bf16_body<0>(A, W, bias, o, blockIdx.x * 128, blockIdx.y * 128);
}

__global__ __launch_bounds__(256) void gemm_proj(
    const unsigned short* __restrict__ xh, const unsigned short* __restrict__ Wo,
    const float* __restrict__ bo, float* __restrict__ out)
{
    gemm_bf16_body<1>(xh, Wo, bo, out, blockIdx.x * 128, blockIdx.y * 128);
}

// ---------------------------------------------------------------------------
// Transpose V: [b,h,s,d] bf16 -> Vt [b,h,d,s] bf16
// ---------------------------------------------------------------------------
__global__ __launch_bounds__(256) void transpose_v(const unsigned short* __restrict__ Vb,
                                                   unsigned short* __restrict__ Vt)
{
    __shared__ __align__(16) unsigned short T[64][72];
    int tid = threadIdx.x;
    int s0 = blockIdx.x * 64;
    int bh = blockIdx.z * 16 + blockIdx.y;
#pragma unroll
    for (int p = 0; p < 2; ++p) {
        int c = p * 256 + tid;
        int row = c >> 3, kc = (c & 7) * 8;
        uint4 v = *(const uint4*)(Vb + ((size_t)bh * 512 + s0 + row) * 64 + kc);
        *(uint4*)&T[row][kc] = v;
    }
    __syncthreads();
#pragma unroll
    for (int p = 0; p < 2; ++p) {
        int c = p * 256 + tid;
        int d = c >> 3, sc = (c & 7) * 8;
        unsigned vv[4];
#pragma unroll
        for (int i = 0; i < 4; ++i) {
            unsigned lo = T[sc + 2*i][d];
            unsigned hi = T[sc + 2*i + 1][d];
            vv[i] = lo | (hi << 16);
        }
        uint4 o; o.x = vv[0]; o.y = vv[1]; o.z = vv[2]; o.w = vv[3];
        *(uint4*)(Vt + ((size_t)bh * 64 + d) * 512 + s0 + sc) = o;
    }
}

// ---------------------------------------------------------------------------
// Attention (unchanged this round)
// ---------------------------------------------------------------------------
__global__ __launch_bounds__(256, 2) void attn_kernel(
    const unsigned short* __restrict__ Qb, const unsigned short* __restrict__ Kb,
    const unsigned short* __restrict__ Vt, const unsigned short* __restrict__ G,
    const int* __restrict__ mask, const float* __restrict__ cw,
    const float* __restrict__ cb, float* __restrict__ attn_out,
    unsigned short* __restrict__ xh)
{
    __shared__ __align__(16) unsigned short Qs[64][72];
    __shared__ __align__(16) unsigned short Ks[128][72];
    __shared__ __align__(16) unsigned short Vs[64][40];
    __shared__ __align__(16) unsigned short Ps[4][16][40];
    __shared__ int s_mask[512];

    int tid = threadIdx.x;
    int lane = tid & 63, w = tid >> 6;
    int lanelo = lane & 15, hi8 = (lane >> 4) * 8;
    int qt = blockIdx.x, h = blockIdx.y, b = blockIdx.z;
    int bh = b * 16 + h;
    float qs  = cw[0] * 0.125f;
    float cbv = cb[0];

    s_mask[tid]       = mask[b * 512 + tid];
    s_mask[tid + 256] = mask[b * 512 + tid + 256];
#pragma unroll
    for (int p = 0; p < 2; ++p) {
        int c = p * 256 + tid;
        int row = c >> 3, kc = (c & 7) * 8;
        uint4 v = *(const uint4*)(Qb + ((size_t)bh * 512 + qt * 64 + row) * 64 + kc);
        *(uint4*)&Qs[row][kc] = v;
    }
    __syncthreads();

    short8 aq[2];
    aq[0] = *(const short8*)&Qs[w * 16 + lanelo][hi8];
    aq[1] = *(const short8*)&Qs[w * 16 + lanelo][32 + hi8];
    int qrow = qt * 64 + w * 16 + (lane >> 4) * 4;

    float P[32][4];
#pragma unroll
    for (int kt = 0; kt < 4; ++kt) {
        __syncthreads();
#pragma unroll
        for (int p = 0; p < 4; ++p) {
            int c = p * 256 + tid;
            int row = c >> 3, kc = (c & 7) * 8;
            uint4 v = *(const uint4*)(Kb + ((size_t)bh * 512 + kt * 128 + row) * 64 + kc);
            *(uint4*)&Ks[row][kc] = v;
        }
        __syncthreads();
#pragma unroll
        for (int j = 0; j < 8; ++j) {
            short8 b0 = *(const short8*)&Ks[j * 16 + lanelo][hi8];
            short8 b1 = *(const short8*)&Ks[j * 16 + lanelo][32 + hi8];
            f32x4 acc; acc[0] = 0.f; acc[1] = 0.f; acc[2] = 0.f; acc[3] = 0.f;
            acc = __builtin_amdgcn_mfma_f32_16x16x32_bf16(aq[0], b0, acc, 0, 0, 0);
            acc = __builtin_amdgcn_mfma_f32_16x16x32_bf16(aq[1], b1, acc, 0, 0, 0);
            int jj = kt * 8 + j;
            int kcol = jj * 16 + lanelo;
            int mk = s_mask[kcol];
            const unsigned short* gp = G + ((size_t)bh * 512 + qrow) * 512 + kcol;
#pragma unroll
            for (int r = 0; r < 4; ++r) {
                float e = qs * acc[r] + bf2f(gp[(size_t)r * 512]) + cbv;
                e = fmaxf(e, 0.f);
                P[jj][r] = mk ? __expf(e) : 0.f;
            }
        }
    }

    float inv[4];
#pragma unroll
    for (int r = 0; r < 4; ++r) {
        float s = 0.f;
#pragma unroll
        for (int jj = 0; jj < 32; ++jj) s += P[jj][r];
        s += __shfl_xor(s, 1, 64);
        s += __shfl_xor(s, 2, 64);
        s += __shfl_xor(s, 4, 64);
        s += __shfl_xor(s, 8, 64);
        inv[r] = 1.0f / s;
    }

    {
        float* ap = attn_out + ((size_t)bh * 512 + qrow) * 512 + lanelo;
#pragma unroll
        for (int jj = 0; jj < 32; ++jj)
#pragma unroll
            for (int r = 0; r < 4; ++r)
                ap[(size_t)r * 512 + jj * 16] = P[jj][r] * inv[r];
    }

    f32x4 xacc[4];
#pragma unroll
    for (int jf = 0; jf < 4; ++jf) { xacc[jf][0]=0.f; xacc[jf][1]=0.f; xacc[jf][2]=0.f; xacc[jf][3]=0.f; }
#pragma unroll
    for (int ks = 0; ks < 16; ++ks) {
        __syncthreads();
        {
            int d = tid >> 2, kc = (tid & 3) * 8;
            uint4 v = *(const uint4*)(Vt + ((size_t)bh * 64 + d) * 512 + ks * 32 + kc);
            *(uint4*)&Vs[d][kc] = v;
        }
#pragma unroll
        for (int ff = 0; ff < 2; ++ff) {
            int f = ks * 2 + ff;
#pragma unroll
            for (int r = 0; r < 4; ++r)
                Ps[w][(lane >> 4) * 4 + r][ff * 16 + lanelo] = f2bf(P[f][r]);
        }
        __syncthreads();
        short8 ap8 = *(const short8*)&Ps[w][lanelo][hi8];
#pragma unroll
        for (int jf = 0; jf < 4; ++jf) {
            short8 bv = *(const short8*)&Vs[jf * 16 + lanelo][hi8];
            xacc[jf] = __builtin_amdgcn_mfma_f32_16x16x32_bf16(ap8, bv, xacc[jf], 0, 0, 0);
        }
    }

#pragma unroll
    for (int jf = 0; jf < 4; ++jf) {
        int d = jf * 16 + lanelo;
#pragma unroll
        for (int r = 0; r < 4; ++r) {
            float val = xacc[jf][r] * inv[r];
            xh[((size_t)b * 512 + qrow + r) * 1024 + h * 64 + d] = f2bf(val);
        }
    }
}

// ---------------------------------------------------------------------------
extern "C" void kernel_launch(void* const* d_in, const int* in_sizes, int n_in,
                              void* d_out, int out_size, void* d_ws, size_t ws_size,
                              hipStream_t stream) {
    (void)in_sizes; (void)n_in; (void)out_size; (void)ws_size;
    const float* query    = (const float*)d_in[0];
    const float* key      = (const float*)d_in[1];
    const float* value    = (const float*)d_in[2];
    const int*   dist_adj = (const int*)d_in[3];
    const float* spk      = (const float*)d_in[4];
    const int*   disc_adj = (const int*)d_in[5];
    const int*   cooc_adj = (const int*)d_in[6];
    const int*   maskp    = (const int*)d_in[7];
    const float* Wq = (const float*)d_in[8];  const float* bq = (const float*)d_in[9];
    const float* Wk = (const float*)d_in[10]; const float* bk = (const float*)d_in[11];
    const float* Wv = (const float*)d_in[12]; const float* bv = (const float*)d_in[13];
    const float* Wo = (const float*)d_in[14]; const float* bo = (const float*)d_in[15];
    const float* dist_emb = (const float*)d_in[16];
    const float* disc_emb = (const float*)d_in[17];
    const float* cooc_emb = (const float*)d_in[18];
    const float* fcw = (const float*)d_in[19];
    const float* fcb = (const float*)d_in[20];
    const float* cw  = (const float*)d_in[21];
    const float* cbp = (const float*)d_in[22];

    char* w = (char*)d_ws;
    unsigned short* Qb  = (unsigned short*)(w);                   //  8 MB
    unsigned short* Kb  = (unsigned short*)(w + 8388608);         //  8 MB
    unsigned short* Vb  = (unsigned short*)(w + 16777216);        //  8 MB
    unsigned short* Vt  = (unsigned short*)(w + 25165824);        //  8 MB
    unsigned short* xh  = (unsigned short*)(w + 33554432);        //  8 MB
    unsigned short* G   = (unsigned short*)(w + 41943040);        // 64 MB
    unsigned short* Abf = G;                                      // alias: used before feat
    unsigned short* Wbf = (unsigned short*)(w + 109051904);       //  8 MB

    float* out_x    = (float*)d_out;
    float* attn_out = ((float*)d_out) + 4194304;

    cvt_qkv<<<dim3(2048, 1, 3), 256, 0, stream>>>(query, key, value, Abf);
    cvt_w<<<dim3(512, 1, 4), 256, 0, stream>>>(Wq, Wk, Wv, Wo, Wbf);
    gemm_qkv<<<dim3(32, 8, 3), 256, 0, stream>>>(Abf, Wbf, bq, bk, bv, Qb, Kb, Vb);
    transpose_v<<<dim3(8, 16, 8), 256, 0, stream>>>(Vb, Vt);
    feat_kernel<<<2048, 256, 0, stream>>>(dist_adj, spk, disc_adj, cooc_adj,
                                          dist_emb, disc_emb, cooc_emb, fcw, fcb, cw, G);
    attn_kernel<<<dim3(8, 16, 8), 256, 0, stream>>>(Qb, Kb, Vt, G, maskp, cw, cbp,
                                                    attn_out, xh);
    gemm_proj<<<dim3(32, 8), 256, 0, stream>>>(xh, Wbf + 3145728, bo, out_x);
}